// Round 1
// baseline (1783.377 us; speedup 1.0000x reference)
//
#include <hip/hip_runtime.h>
#include <math.h>

#define NN 50000
#define EE 1600000
#define CIN 32
#define HIDDEN 128
#define LATENT 64
#define NM 1600000   // N * C_IN (decoder output elements)

// ---- workspace layout (bytes, all offsets multiple of 256) ----
#define OFF_CNT     0u           // N ints
#define OFF_CURSOR  204800u      // N ints
#define OFF_ROWPTR  409600u      // N+1 ints
#define OFF_DIS     614400u      // N floats
#define OFF_CSRSRC  819200u      // E ints
#define OFF_CSRNRM  7219200u     // E floats
#define OFF_HA      13619200u    // N*128 floats
#define OFF_HB      39219200u    // N*128 floats
#define OFF_GSUM    64819200u    // 128 floats
#define OFF_DVEC    64819712u    // 128 floats

__global__ void k_count(const int* __restrict__ dst, int* __restrict__ cnt) {
    int e = blockIdx.x * 256 + threadIdx.x;
    if (e < EE) atomicAdd(&cnt[dst[e]], 1);
}

__global__ void k_dis(const int* __restrict__ cnt, float* __restrict__ dis) {
    int i = blockIdx.x * 256 + threadIdx.x;
    if (i < NN) dis[i] = rsqrtf((float)(cnt[i] + 1));  // +1 self-loop; deg>=1 always
}

// single-block exclusive scan of cnt -> rowptr
__global__ void k_scan(const int* __restrict__ cnt, int* __restrict__ rowptr) {
    __shared__ int sdata[1024];
    __shared__ int running;
    int t = threadIdx.x;
    if (t == 0) running = 0;
    __syncthreads();
    for (int base = 0; base < NN; base += 1024) {
        int i = base + t;
        int v = (i < NN) ? cnt[i] : 0;
        sdata[t] = v;
        __syncthreads();
        for (int off = 1; off < 1024; off <<= 1) {
            int add = (t >= off) ? sdata[t - off] : 0;
            __syncthreads();
            sdata[t] += add;
            __syncthreads();
        }
        if (i < NN) rowptr[i] = running + sdata[t] - v;   // exclusive
        int tot = sdata[1023];
        __syncthreads();
        if (t == 0) running += tot;
        __syncthreads();
    }
    if (t == 0) rowptr[NN] = running;
}

__global__ void k_fill(const int* __restrict__ src, const int* __restrict__ dst,
                       const float* __restrict__ dis, const int* __restrict__ rowptr,
                       int* __restrict__ cursor, int* __restrict__ csr_src,
                       float* __restrict__ csr_nrm) {
    int e = blockIdx.x * 256 + threadIdx.x;
    if (e >= EE) return;
    int d = dst[e], s = src[e];
    int pos = atomicAdd(&cursor[d], 1);
    int slot = rowptr[d] + pos;
    csr_src[slot] = s;
    csr_nrm[slot] = dis[s] * dis[d];
}

// x[N,32] @ W1[32,128] -> hA[N,128]   (8 nodes per 256-thread block)
__global__ void k_gemm1(const float* __restrict__ x, const float* __restrict__ W1,
                        float* __restrict__ hA) {
    __shared__ float xs[8 * 32];
    int t = threadIdx.x;
    int nb = blockIdx.x * 8;
    xs[t] = x[nb * 32 + t];
    __syncthreads();
    int c = t & 127, quad = t >> 7;
    float a0 = 0.f, a1 = 0.f, a2 = 0.f, a3 = 0.f;
    const float* r0 = &xs[(quad * 4 + 0) * 32];
    const float* r1 = &xs[(quad * 4 + 1) * 32];
    const float* r2 = &xs[(quad * 4 + 2) * 32];
    const float* r3 = &xs[(quad * 4 + 3) * 32];
#pragma unroll
    for (int k = 0; k < 32; k++) {
        float w = W1[k * 128 + c];
        a0 = fmaf(r0[k], w, a0);
        a1 = fmaf(r1[k], w, a1);
        a2 = fmaf(r2[k], w, a2);
        a3 = fmaf(r3[k], w, a3);
    }
    int n0 = nb + quad * 4;
    hA[(n0 + 0) * 128 + c] = a0;
    hA[(n0 + 1) * 128 + c] = a1;
    hA[(n0 + 2) * 128 + c] = a2;
    hA[(n0 + 3) * 128 + c] = a3;
}

// hB[N,128] @ W2[128,128] -> hA[N,128]
__global__ void k_gemm2(const float* __restrict__ hB, const float* __restrict__ W2,
                        float* __restrict__ hA) {
    __shared__ float rs[8 * 128];
    int t = threadIdx.x;
    int nb = blockIdx.x * 8;
#pragma unroll
    for (int r = 0; r < 4; r++) rs[t + r * 256] = hB[nb * 128 + t + r * 256];
    __syncthreads();
    int c = t & 127, quad = t >> 7;
    float a0 = 0.f, a1 = 0.f, a2 = 0.f, a3 = 0.f;
    const float* r0 = &rs[(quad * 4 + 0) * 128];
    const float* r1 = &rs[(quad * 4 + 1) * 128];
    const float* r2 = &rs[(quad * 4 + 2) * 128];
    const float* r3 = &rs[(quad * 4 + 3) * 128];
#pragma unroll 8
    for (int k = 0; k < 128; k++) {
        float w = W2[k * 128 + c];
        a0 = fmaf(r0[k], w, a0);
        a1 = fmaf(r1[k], w, a1);
        a2 = fmaf(r2[k], w, a2);
        a3 = fmaf(r3[k], w, a3);
    }
    int n0 = nb + quad * 4;
    hA[(n0 + 0) * 128 + c] = a0;
    hA[(n0 + 1) * 128 + c] = a1;
    hA[(n0 + 2) * 128 + c] = a2;
    hA[(n0 + 3) * 128 + c] = a3;
}

// layer-1 aggregation: out = relu(agg(h) + bias).  32 lanes per node, float4 channels.
__global__ void k_agg1(const float* __restrict__ h, const float* __restrict__ dis,
                       const int* __restrict__ rowptr, const int* __restrict__ csr_src,
                       const float* __restrict__ csr_nrm, const float* __restrict__ bias,
                       float* __restrict__ outp) {
    int t = threadIdx.x;
    int c4 = t & 31;
    int i = blockIdx.x * 8 + (t >> 5);
    if (i >= NN) return;
    const float4* h4 = (const float4*)h;
    float di = dis[i];
    float sn = di * di;
    float4 acc = h4[i * 32 + c4];
    acc.x *= sn; acc.y *= sn; acc.z *= sn; acc.w *= sn;
    int beg = rowptr[i], end = rowptr[i + 1];
    for (int s = beg; s < end; s++) {
        int sc = csr_src[s];
        float w = csr_nrm[s];
        float4 hv = h4[sc * 32 + c4];
        acc.x = fmaf(hv.x, w, acc.x);
        acc.y = fmaf(hv.y, w, acc.y);
        acc.z = fmaf(hv.z, w, acc.z);
        acc.w = fmaf(hv.w, w, acc.w);
    }
    float4 bv = ((const float4*)bias)[c4];
    acc.x = fmaxf(acc.x + bv.x, 0.f);
    acc.y = fmaxf(acc.y + bv.y, 0.f);
    acc.z = fmaxf(acc.z + bv.z, 0.f);
    acc.w = fmaxf(acc.w + bv.w, 0.f);
    ((float4*)outp)[i * 32 + c4] = acc;
}

// layer-2 aggregation fused with column-mean accumulation (rows never stored)
__global__ void k_agg2(const float* __restrict__ h, const float* __restrict__ dis,
                       const int* __restrict__ rowptr, const int* __restrict__ csr_src,
                       const float* __restrict__ csr_nrm, const float* __restrict__ bias,
                       float* __restrict__ gsum) {
    int t = threadIdx.x;
    int c4 = t & 31;
    int slot8 = t >> 5;
    const float4* h4 = (const float4*)h;
    float4 bv = ((const float4*)bias)[c4];
    float4 sum; sum.x = sum.y = sum.z = sum.w = 0.f;
    for (int i = blockIdx.x * 8 + slot8; i < NN; i += gridDim.x * 8) {
        float di = dis[i];
        float sn = di * di;
        float4 acc = h4[i * 32 + c4];
        acc.x *= sn; acc.y *= sn; acc.z *= sn; acc.w *= sn;
        int beg = rowptr[i], end = rowptr[i + 1];
        for (int s = beg; s < end; s++) {
            int sc = csr_src[s];
            float w = csr_nrm[s];
            float4 hv = h4[sc * 32 + c4];
            acc.x = fmaf(hv.x, w, acc.x);
            acc.y = fmaf(hv.y, w, acc.y);
            acc.z = fmaf(hv.z, w, acc.z);
            acc.w = fmaf(hv.w, w, acc.w);
        }
        sum.x += fmaxf(acc.x + bv.x, 0.f);
        sum.y += fmaxf(acc.y + bv.y, 0.f);
        sum.z += fmaxf(acc.z + bv.z, 0.f);
        sum.w += fmaxf(acc.w + bv.w, 0.f);
    }
    __shared__ float4 sdata[256];
    sdata[t] = sum;
    __syncthreads();
    if (t < 32) {
        float4 tot = sdata[t];
#pragma unroll
        for (int s = 1; s < 8; s++) {
            float4 v = sdata[t + s * 32];
            tot.x += v.x; tot.y += v.y; tot.z += v.z; tot.w += v.w;
        }
        atomicAdd(&gsum[c4 * 4 + 0], tot.x);
        atomicAdd(&gsum[c4 * 4 + 1], tot.y);
        atomicAdd(&gsum[c4 * 4 + 2], tot.z);
        atomicAdd(&gsum[c4 * 4 + 3], tot.w);
    }
}

// mean -> mu/logvar -> z -> d   (single block, 128 threads)
__global__ void k_head(const float* __restrict__ gsum, const float* __restrict__ eps,
                       const float* __restrict__ Wmu, const float* __restrict__ bmu,
                       const float* __restrict__ Wlv, const float* __restrict__ blv,
                       const float* __restrict__ Wd1, const float* __restrict__ bd1,
                       float* __restrict__ outp, float* __restrict__ dvec) {
    __shared__ float g[128];
    __shared__ float zs[64];
    int t = threadIdx.x;
    g[t] = gsum[t] * (1.0f / (float)NN);
    __syncthreads();
    if (t < 64) {
        float mu = bmu[t], lv = blv[t];
#pragma unroll 8
        for (int k = 0; k < 128; k++) {
            float gk = g[k];
            mu = fmaf(gk, Wmu[k * 64 + t], mu);
            lv = fmaf(gk, Wlv[k * 64 + t], lv);
        }
        float z = mu + eps[t] * expf(0.5f * lv);
        outp[NM + t] = mu;
        outp[NM + 64 + t] = lv;
        zs[t] = z;
    }
    __syncthreads();
    float dv = bd1[t];
#pragma unroll 8
    for (int k = 0; k < 64; k++) dv = fmaf(zs[k], Wd1[k * 128 + t], dv);
    dvec[t] = fmaxf(dv, 0.f);
}

// recon[n] = sum_k d[k]*Wd2[k,n] + bd2[n]   (float4 per thread, streams 819 MB)
__global__ void k_dec(const float* __restrict__ dvec, const float* __restrict__ Wd2,
                      const float* __restrict__ bd2, float* __restrict__ outp) {
    __shared__ float d[128];
    int t = threadIdx.x;
    if (t < 128) d[t] = dvec[t];
    __syncthreads();
    int n0 = (blockIdx.x * 256 + t) * 4;
    if (n0 >= NM) return;
    float4 acc = *(const float4*)(bd2 + n0);
#pragma unroll 8
    for (int k = 0; k < 128; k++) {
        float dk = d[k];
        float4 w = *(const float4*)(Wd2 + (size_t)k * NM + n0);
        acc.x = fmaf(dk, w.x, acc.x);
        acc.y = fmaf(dk, w.y, acc.y);
        acc.z = fmaf(dk, w.z, acc.z);
        acc.w = fmaf(dk, w.w, acc.w);
    }
    *(float4*)(outp + n0) = acc;
}

extern "C" void kernel_launch(void* const* d_in, const int* in_sizes, int n_in,
                              void* d_out, int out_size, void* d_ws, size_t ws_size,
                              hipStream_t stream) {
    const float* x   = (const float*)d_in[0];
    const int*   ei  = (const int*)d_in[1];
    const float* eps = (const float*)d_in[2];
    const float* W1  = (const float*)d_in[3];
    const float* b1  = (const float*)d_in[4];
    const float* W2  = (const float*)d_in[5];
    const float* b2  = (const float*)d_in[6];
    const float* Wmu = (const float*)d_in[7];
    const float* bmu = (const float*)d_in[8];
    const float* Wlv = (const float*)d_in[9];
    const float* blv = (const float*)d_in[10];
    const float* Wd1 = (const float*)d_in[11];
    const float* bd1 = (const float*)d_in[12];
    const float* Wd2 = (const float*)d_in[13];
    const float* bd2 = (const float*)d_in[14];
    float* outp = (float*)d_out;
    char* ws = (char*)d_ws;

    int*   cnt     = (int*)(ws + OFF_CNT);
    int*   cursor  = (int*)(ws + OFF_CURSOR);
    int*   rowptr  = (int*)(ws + OFF_ROWPTR);
    float* dis     = (float*)(ws + OFF_DIS);
    int*   csr_src = (int*)(ws + OFF_CSRSRC);
    float* csr_nrm = (float*)(ws + OFF_CSRNRM);
    float* hA      = (float*)(ws + OFF_HA);
    float* hB      = (float*)(ws + OFF_HB);
    float* gsum    = (float*)(ws + OFF_GSUM);
    float* dvec    = (float*)(ws + OFF_DVEC);

    const int* srcp = ei;
    const int* dstp = ei + EE;

    hipMemsetAsync(cnt, 0, NN * sizeof(int), stream);
    hipMemsetAsync(cursor, 0, NN * sizeof(int), stream);
    hipMemsetAsync(gsum, 0, 128 * sizeof(float), stream);

    k_count<<<EE / 256, 256, 0, stream>>>(dstp, cnt);
    k_dis<<<(NN + 255) / 256, 256, 0, stream>>>(cnt, dis);
    k_scan<<<1, 1024, 0, stream>>>(cnt, rowptr);
    k_fill<<<EE / 256, 256, 0, stream>>>(srcp, dstp, dis, rowptr, cursor, csr_src, csr_nrm);

    k_gemm1<<<NN / 8, 256, 0, stream>>>(x, W1, hA);
    k_agg1<<<NN / 8, 256, 0, stream>>>(hA, dis, rowptr, csr_src, csr_nrm, b1, hB);
    k_gemm2<<<NN / 8, 256, 0, stream>>>(hB, W2, hA);
    k_agg2<<<512, 256, 0, stream>>>(hA, dis, rowptr, csr_src, csr_nrm, b2, gsum);
    k_head<<<1, 128, 0, stream>>>(gsum, eps, Wmu, bmu, Wlv, blv, Wd1, bd1, outp, dvec);
    k_dec<<<(NM / 4 + 255) / 256, 256, 0, stream>>>(dvec, Wd2, bd2, outp);
}

// Round 2
// 1451.370 us; speedup vs baseline: 1.2288x; 1.2288x over previous
//
#include <hip/hip_runtime.h>
#include <math.h>

#define NN 50000
#define EE 1600000
#define CIN 32
#define HIDDEN 128
#define LATENT 64
#define NM 1600000   // N * C_IN (decoder output elements)

// ---- workspace layout (bytes, offsets multiple of 256) ----
#define OFF_CNT     0u          // N ints
#define OFF_CURSOR  204800u     // N ints
#define OFF_ROWPTR  409600u     // N+1 ints
#define OFF_DIS     614400u     // N floats
#define OFF_BSUM    819200u     // 256 ints
#define OFF_CSRSRC  820224u     // E ints
#define OFF_CSRNRM  7220224u    // E floats
#define OFF_XA      13620224u   // N*32 floats  (aggregated x)
#define OFF_Q       20020224u   // N*128 bf16   (relu layer-1 output)
#define OFF_QA      32820224u   // N*128 floats (aggregated q)
#define OFF_GSUM    58420224u   // 128 floats
#define OFF_DVEC    58420736u   // 128 floats

static __device__ __forceinline__ unsigned short f2bf_rne(float f) {
    unsigned int u = __float_as_uint(f);
    u += 0x7FFFu + ((u >> 16) & 1u);
    return (unsigned short)(u >> 16);
}

__global__ void k_count(const int* __restrict__ dst, int* __restrict__ cnt) {
    int e = blockIdx.x * 256 + threadIdx.x;
    if (e < EE) atomicAdd(&cnt[dst[e]], 1);
}

__global__ void k_dis(const int* __restrict__ cnt, float* __restrict__ dis) {
    int i = blockIdx.x * 256 + threadIdx.x;
    if (i < NN) dis[i] = rsqrtf((float)(cnt[i] + 1));  // +1 self-loop
}

// hierarchical scan, stage 1: per-block exclusive scan + block totals
__global__ void k_scan_local(const int* __restrict__ cnt, int* __restrict__ rowptr,
                             int* __restrict__ bsum) {
    __shared__ int s[256];
    int t = threadIdx.x;
    int i = blockIdx.x * 256 + t;
    int v = (i < NN) ? cnt[i] : 0;
    s[t] = v;
    __syncthreads();
    for (int off = 1; off < 256; off <<= 1) {
        int a = (t >= off) ? s[t - off] : 0;
        __syncthreads();
        s[t] += a;
        __syncthreads();
    }
    if (i < NN) rowptr[i] = s[t] - v;          // exclusive within block
    if (t == 255) bsum[blockIdx.x] = s[255];
}

// stage 2: single-block scan of the 196 block totals (in-place -> exclusive)
__global__ void k_scan_bsum(int* __restrict__ bsum, int* __restrict__ rowptr, int nblk) {
    __shared__ int s[256];
    int t = threadIdx.x;
    int v = (t < nblk) ? bsum[t] : 0;
    s[t] = v;
    __syncthreads();
    for (int off = 1; off < 256; off <<= 1) {
        int a = (t >= off) ? s[t - off] : 0;
        __syncthreads();
        s[t] += a;
        __syncthreads();
    }
    if (t < nblk) bsum[t] = s[t] - v;          // exclusive
    if (t == 255) rowptr[NN] = s[255];         // total = EE
}

// stage 3: add block offsets
__global__ void k_scan_add(int* __restrict__ rowptr, const int* __restrict__ bsum) {
    int i = blockIdx.x * 256 + threadIdx.x;
    if (i < NN) rowptr[i] += bsum[blockIdx.x];
}

__global__ void k_fill(const int* __restrict__ src, const int* __restrict__ dst,
                       const float* __restrict__ dis, const int* __restrict__ rowptr,
                       int* __restrict__ cursor, int* __restrict__ csr_src,
                       float* __restrict__ csr_nrm) {
    int e = blockIdx.x * 256 + threadIdx.x;
    if (e >= EE) return;
    int d = dst[e], s = src[e];
    int pos = atomicAdd(&cursor[d], 1);
    int slot = rowptr[d] + pos;
    csr_src[slot] = s;
    csr_nrm[slot] = dis[s] * dis[d];
}

// layer-1 propagate on RAW x (agg commutes with W1): xa = D^-1/2 (A+I) D^-1/2 x
// 8 lanes per node (32 fp32 ch = 8 float4), 32 nodes per 256-thread block.
__global__ void k_aggx(const float* __restrict__ x, const float* __restrict__ dis,
                       const int* __restrict__ rowptr, const int* __restrict__ csr_src,
                       const float* __restrict__ csr_nrm, float* __restrict__ xa) {
    int t = threadIdx.x;
    int c4 = t & 7;
    int i = blockIdx.x * 32 + (t >> 3);
    if (i >= NN) return;
    const float4* x4 = (const float4*)x;
    float di = dis[i];
    float sn = di * di;
    float4 acc = x4[i * 8 + c4];
    acc.x *= sn; acc.y *= sn; acc.z *= sn; acc.w *= sn;
    int beg = rowptr[i], end = rowptr[i + 1];
    for (int s = beg; s < end; s++) {
        int sc = csr_src[s];
        float w = csr_nrm[s];
        float4 v = x4[sc * 8 + c4];
        acc.x = fmaf(v.x, w, acc.x);
        acc.y = fmaf(v.y, w, acc.y);
        acc.z = fmaf(v.z, w, acc.z);
        acc.w = fmaf(v.w, w, acc.w);
    }
    ((float4*)xa)[i * 8 + c4] = acc;
}

// q = relu(xa @ W1 + b1) stored bf16 [N,128].  8 nodes/block.
__global__ void k_gemm1h(const float* __restrict__ xa, const float* __restrict__ W1,
                         const float* __restrict__ b1, unsigned short* __restrict__ q) {
    __shared__ float xs[8 * 32];
    int t = threadIdx.x;
    int nb = blockIdx.x * 8;
    xs[t] = xa[nb * 32 + t];
    __syncthreads();
    int c = t & 127, quad = t >> 7;
    float a0 = 0.f, a1 = 0.f, a2 = 0.f, a3 = 0.f;
    const float* r0 = &xs[(quad * 4 + 0) * 32];
    const float* r1 = &xs[(quad * 4 + 1) * 32];
    const float* r2 = &xs[(quad * 4 + 2) * 32];
    const float* r3 = &xs[(quad * 4 + 3) * 32];
#pragma unroll
    for (int k = 0; k < 32; k++) {
        float w = W1[k * 128 + c];
        a0 = fmaf(r0[k], w, a0);
        a1 = fmaf(r1[k], w, a1);
        a2 = fmaf(r2[k], w, a2);
        a3 = fmaf(r3[k], w, a3);
    }
    float bc = b1[c];
    int n0 = nb + quad * 4;
    q[(n0 + 0) * 128 + c] = f2bf_rne(fmaxf(a0 + bc, 0.f));
    q[(n0 + 1) * 128 + c] = f2bf_rne(fmaxf(a1 + bc, 0.f));
    q[(n0 + 2) * 128 + c] = f2bf_rne(fmaxf(a2 + bc, 0.f));
    q[(n0 + 3) * 128 + c] = f2bf_rne(fmaxf(a3 + bc, 0.f));
}

// layer-2 propagate on q (bf16, 256 B/row): qa = D^-1/2 (A+I) D^-1/2 q   (fp32 accum)
// 32 lanes per node (4 bf16 per lane), 8 nodes/block.
__global__ void k_agg2(const unsigned short* __restrict__ q, const float* __restrict__ dis,
                       const int* __restrict__ rowptr, const int* __restrict__ csr_src,
                       const float* __restrict__ csr_nrm, float* __restrict__ qa) {
    int t = threadIdx.x;
    int c4 = t & 31;
    int i = blockIdx.x * 8 + (t >> 5);
    if (i >= NN) return;
    const uint2* q2 = (const uint2*)q;
    float di = dis[i];
    float sn = di * di;
    uint2 w = q2[i * 32 + c4];
    float4 acc;
    acc.x = sn * __uint_as_float(w.x << 16);
    acc.y = sn * __uint_as_float(w.x & 0xFFFF0000u);
    acc.z = sn * __uint_as_float(w.y << 16);
    acc.w = sn * __uint_as_float(w.y & 0xFFFF0000u);
    int beg = rowptr[i], end = rowptr[i + 1];
    for (int s = beg; s < end; s++) {
        int sc = csr_src[s];
        float nw = csr_nrm[s];
        uint2 v = q2[sc * 32 + c4];
        acc.x = fmaf(__uint_as_float(v.x << 16), nw, acc.x);
        acc.y = fmaf(__uint_as_float(v.x & 0xFFFF0000u), nw, acc.y);
        acc.z = fmaf(__uint_as_float(v.y << 16), nw, acc.z);
        acc.w = fmaf(__uint_as_float(v.y & 0xFFFF0000u), nw, acc.w);
    }
    ((float4*)qa)[i * 32 + c4] = acc;
}

// out2 = relu(qa @ W2 + b2); accumulate column sums into gsum (mean later).
// Grid-stride over groups of 8 nodes; h2 never materialized.
__global__ void k_gemm2m(const float* __restrict__ qa, const float* __restrict__ W2,
                         const float* __restrict__ b2, float* __restrict__ gsum) {
    __shared__ float rs[8 * 128];
    __shared__ float red[128];
    int t = threadIdx.x;
    int c = t & 127, quad = t >> 7;
    float bc = b2[c];
    float colsum = 0.f;
    for (int g = blockIdx.x; g < NN / 8; g += gridDim.x) {
        int nb = g * 8;
#pragma unroll
        for (int r = 0; r < 4; r++) rs[t + r * 256] = qa[nb * 128 + t + r * 256];
        __syncthreads();
        float a0 = 0.f, a1 = 0.f, a2 = 0.f, a3 = 0.f;
        const float* r0 = &rs[(quad * 4 + 0) * 128];
        const float* r1 = &rs[(quad * 4 + 1) * 128];
        const float* r2 = &rs[(quad * 4 + 2) * 128];
        const float* r3 = &rs[(quad * 4 + 3) * 128];
#pragma unroll 8
        for (int k = 0; k < 128; k++) {
            float w = W2[k * 128 + c];
            a0 = fmaf(r0[k], w, a0);
            a1 = fmaf(r1[k], w, a1);
            a2 = fmaf(r2[k], w, a2);
            a3 = fmaf(r3[k], w, a3);
        }
        colsum += fmaxf(a0 + bc, 0.f) + fmaxf(a1 + bc, 0.f) +
                  fmaxf(a2 + bc, 0.f) + fmaxf(a3 + bc, 0.f);
        __syncthreads();
    }
    if (quad == 1) red[c] = colsum;
    __syncthreads();
    if (quad == 0) atomicAdd(&gsum[c], colsum + red[c]);
}

// mean -> mu/logvar -> z -> d   (single block, 128 threads)
__global__ void k_head(const float* __restrict__ gsum, const float* __restrict__ eps,
                       const float* __restrict__ Wmu, const float* __restrict__ bmu,
                       const float* __restrict__ Wlv, const float* __restrict__ blv,
                       const float* __restrict__ Wd1, const float* __restrict__ bd1,
                       float* __restrict__ outp, float* __restrict__ dvec) {
    __shared__ float g[128];
    __shared__ float zs[64];
    int t = threadIdx.x;
    g[t] = gsum[t] * (1.0f / (float)NN);
    __syncthreads();
    if (t < 64) {
        float mu = bmu[t], lv = blv[t];
#pragma unroll 8
        for (int k = 0; k < 128; k++) {
            float gk = g[k];
            mu = fmaf(gk, Wmu[k * 64 + t], mu);
            lv = fmaf(gk, Wlv[k * 64 + t], lv);
        }
        float z = mu + eps[t] * expf(0.5f * lv);
        outp[NM + t] = mu;
        outp[NM + 64 + t] = lv;
        zs[t] = z;
    }
    __syncthreads();
    float dv = bd1[t];
#pragma unroll 8
    for (int k = 0; k < 64; k++) dv = fmaf(zs[k], Wd1[k * 128 + t], dv);
    dvec[t] = fmaxf(dv, 0.f);
}

// recon[n] = sum_k d[k]*Wd2[k,n] + bd2[n]   (float4/thread; streams 819 MB fp32)
__global__ void k_dec(const float* __restrict__ dvec, const float* __restrict__ Wd2,
                      const float* __restrict__ bd2, float* __restrict__ outp) {
    __shared__ float d[128];
    int t = threadIdx.x;
    if (t < 128) d[t] = dvec[t];
    __syncthreads();
    int n0 = (blockIdx.x * 256 + t) * 4;
    if (n0 >= NM) return;
    float4 acc = *(const float4*)(bd2 + n0);
#pragma unroll 8
    for (int k = 0; k < 128; k++) {
        float dk = d[k];
        float4 w = *(const float4*)(Wd2 + (size_t)k * NM + n0);
        acc.x = fmaf(dk, w.x, acc.x);
        acc.y = fmaf(dk, w.y, acc.y);
        acc.z = fmaf(dk, w.z, acc.z);
        acc.w = fmaf(dk, w.w, acc.w);
    }
    *(float4*)(outp + n0) = acc;
}

extern "C" void kernel_launch(void* const* d_in, const int* in_sizes, int n_in,
                              void* d_out, int out_size, void* d_ws, size_t ws_size,
                              hipStream_t stream) {
    const float* x   = (const float*)d_in[0];
    const int*   ei  = (const int*)d_in[1];
    const float* eps = (const float*)d_in[2];
    const float* W1  = (const float*)d_in[3];
    const float* b1  = (const float*)d_in[4];
    const float* W2  = (const float*)d_in[5];
    const float* b2  = (const float*)d_in[6];
    const float* Wmu = (const float*)d_in[7];
    const float* bmu = (const float*)d_in[8];
    const float* Wlv = (const float*)d_in[9];
    const float* blv = (const float*)d_in[10];
    const float* Wd1 = (const float*)d_in[11];
    const float* bd1 = (const float*)d_in[12];
    const float* Wd2 = (const float*)d_in[13];
    const float* bd2 = (const float*)d_in[14];
    float* outp = (float*)d_out;
    char* ws = (char*)d_ws;

    int*   cnt     = (int*)(ws + OFF_CNT);
    int*   cursor  = (int*)(ws + OFF_CURSOR);
    int*   rowptr  = (int*)(ws + OFF_ROWPTR);
    float* dis     = (float*)(ws + OFF_DIS);
    int*   bsum    = (int*)(ws + OFF_BSUM);
    int*   csr_src = (int*)(ws + OFF_CSRSRC);
    float* csr_nrm = (float*)(ws + OFF_CSRNRM);
    float* xa      = (float*)(ws + OFF_XA);
    unsigned short* q = (unsigned short*)(ws + OFF_Q);
    float* qa      = (float*)(ws + OFF_QA);
    float* gsum    = (float*)(ws + OFF_GSUM);
    float* dvec    = (float*)(ws + OFF_DVEC);

    const int* srcp = ei;
    const int* dstp = ei + EE;

    const int SCAN_BLKS = (NN + 255) / 256;  // 196

    hipMemsetAsync(cnt, 0, NN * sizeof(int), stream);
    hipMemsetAsync(cursor, 0, NN * sizeof(int), stream);
    hipMemsetAsync(gsum, 0, 128 * sizeof(float), stream);

    k_count<<<EE / 256, 256, 0, stream>>>(dstp, cnt);
    k_dis<<<SCAN_BLKS, 256, 0, stream>>>(cnt, dis);
    k_scan_local<<<SCAN_BLKS, 256, 0, stream>>>(cnt, rowptr, bsum);
    k_scan_bsum<<<1, 256, 0, stream>>>(bsum, rowptr, SCAN_BLKS);
    k_scan_add<<<SCAN_BLKS, 256, 0, stream>>>(rowptr, bsum);
    k_fill<<<EE / 256, 256, 0, stream>>>(srcp, dstp, dis, rowptr, cursor, csr_src, csr_nrm);

    k_aggx<<<(NN + 31) / 32, 256, 0, stream>>>(x, dis, rowptr, csr_src, csr_nrm, xa);
    k_gemm1h<<<NN / 8, 256, 0, stream>>>(xa, W1, b1, q);
    k_agg2<<<NN / 8, 256, 0, stream>>>(q, dis, rowptr, csr_src, csr_nrm, qa);
    k_gemm2m<<<512, 256, 0, stream>>>(qa, W2, b2, gsum);
    k_head<<<1, 128, 0, stream>>>(gsum, eps, Wmu, bmu, Wlv, blv, Wd1, bd1, outp, dvec);
    k_dec<<<(NM / 4 + 255) / 256, 256, 0, stream>>>(dvec, Wd2, bd2, outp);
}